// Round 16
// baseline (266.142 us; speedup 1.0000x reference)
//
#include <hip/hip_runtime.h>

typedef unsigned short u16;
typedef __attribute__((ext_vector_type(8))) short s16x8;
typedef __attribute__((ext_vector_type(4))) float f32x4;
typedef unsigned uint2v __attribute__((ext_vector_type(2)));

#define B_  2
#define N_  2048
#define D_  1024
#define H_  16
#define DH_ 64
#define M_  4096  // B_*N_

#define S_X (M_ * D_)   // 4M
#define S_W (D_ * D_)   // 1M

// Q pre-scale: 1/sqrt(64) folded with log2(e) so softmax uses raw exp2
#define QSCALE 0.1803368801111204f

// ws layout (u16 offsets). Direct-fp32 path needs only 8M u16 = 16 MiB... 4*S_X*2 = 32 MiB.
#define OFF_QB 0
#define OFF_KB (S_X)
#define OFF_VB (2 * S_X)
#define OFF_XB (3 * S_X)

#if __has_builtin(__builtin_amdgcn_exp2f)
#define EXP2(x) __builtin_amdgcn_exp2f(x)
#else
#define EXP2(x) exp2f(x)
#endif

__device__ __forceinline__ u16 f2bf(float f) {
  unsigned u = __builtin_bit_cast(unsigned, f);
  u += 0x7fffu + ((u >> 16) & 1u);   // RNE
  return (u16)(u >> 16);
}
__device__ __forceinline__ s16x8 pack8(float4 a, float4 b) {
  s16x8 r;
  r[0] = (short)f2bf(a.x); r[1] = (short)f2bf(a.y);
  r[2] = (short)f2bf(a.z); r[3] = (short)f2bf(a.w);
  r[4] = (short)f2bf(b.x); r[5] = (short)f2bf(b.y);
  r[6] = (short)f2bf(b.z); r[7] = (short)f2bf(b.w);
  return r;
}
__device__ __forceinline__ void gl2lds16(const void* g, void* l) {
  __builtin_amdgcn_global_load_lds(
      (const __attribute__((address_space(1))) void*)g,
      (__attribute__((address_space(3))) void*)l, 16, 0, 0);
}
// permlane swaps (VALU pipe): a,b updated in place.
__device__ __forceinline__ void pl32(unsigned &a, unsigned &b) {
#if __has_builtin(__builtin_amdgcn_permlane32_swap)
  uint2v r = __builtin_amdgcn_permlane32_swap(a, b, 0, 0);
  a = r[0]; b = r[1];
#else
  asm("v_permlane32_swap_b32 %0, %1" : "+v"(a), "+v"(b));
#endif
}
__device__ __forceinline__ void pl16(unsigned &a, unsigned &b) {
#if __has_builtin(__builtin_amdgcn_permlane16_swap)
  uint2v r = __builtin_amdgcn_permlane16_swap(a, b, 0, 0);
  a = r[0]; b = r[1];
#else
  asm("v_permlane16_swap_b32 %0, %1" : "+v"(a), "+v"(b));
#endif
}

// ---- QKV direct from fp32: VGPR-pack staging (same f2bf as cvt path ->
// bit-identical outputs). XCD remap (bijective over 768): all 8 n-tiles
// sharing one A-panel land on ONE XCD. z==2 (V) epilogue: LDS tile-transpose
// so Vt writes are coalesced 16B stores (ported from the bf16 kernel).
__global__ __launch_bounds__(256, 3)
void qkv_gemm_f32(const float* __restrict__ xq, const float* __restrict__ xk,
                  const float* __restrict__ xv, const float* __restrict__ Wq,
                  const float* __restrict__ Wk, const float* __restrict__ Wv,
                  const float* __restrict__ bq, const float* __restrict__ bk,
                  const float* __restrict__ bv, u16* __restrict__ ws) {
  __shared__ __align__(16) u16 As[128 * 32];
  __shared__ __align__(16) u16 Bs[128 * 32];
  __shared__ __align__(16) u16 Ts[128][136];   // transpose staging (z==2 only)
  const int flat = (blockIdx.z * 32 + blockIdx.y) * 8 + blockIdx.x;
  const int u = flat & 7, v = flat >> 3;        // u -> XCD, v in [0,96)
  const int bxn = v & 7;                        // n-tile
  const int byz = u * 12 + (v >> 3);            // [0,96)
  const int z = byz >> 5, bym = byz & 31;       // z in [0,3), m-tile in [0,32)

  const float* A    = (z == 0) ? xq : (z == 1) ? xk : xv;
  const float* W    = (z == 0) ? Wq : (z == 1) ? Wk : Wv;
  const float* bias = (z == 0) ? bq : (z == 1) ? bk : bv;
  u16* out = ws + (size_t)z * S_X;
  const float scale = (z == 0) ? QSCALE : 1.0f;

  const int tid  = threadIdx.x;
  const int wave = tid >> 6, lane = tid & 63;
  const int quad = lane >> 4, l16 = lane & 15;
  const int wr = wave >> 1, wc = wave & 1;
  const int m0 = bym * 128, n0 = bxn * 128;

  f32x4 acc[4][4];
#pragma unroll
  for (int i = 0; i < 4; ++i)
#pragma unroll
    for (int j = 0; j < 4; ++j) acc[i][j] = {0.f, 0.f, 0.f, 0.f};

  for (int kt = 0; kt < D_ / 32; ++kt) {
    const int kb = kt * 32;
#pragma unroll
    for (int call = 0; call < 2; ++call) {
      const int c = call * 256 + wave * 64 + lane;
      const int row = c >> 2, col = (c & 3) * 8;
      const float4 a0 = *(const float4*)&A[(size_t)(m0 + row) * D_ + kb + col];
      const float4 a1 = *(const float4*)&A[(size_t)(m0 + row) * D_ + kb + col + 4];
      const float4 w0 = *(const float4*)&W[(size_t)(n0 + row) * D_ + kb + col];
      const float4 w1 = *(const float4*)&W[(size_t)(n0 + row) * D_ + kb + col + 4];
      *(s16x8*)&As[c * 8] = pack8(a0, a1);
      *(s16x8*)&Bs[c * 8] = pack8(w0, w1);
    }
    __syncthreads();

    s16x8 af[4], bf[4];
#pragma unroll
    for (int i = 0; i < 4; ++i) {
      af[i] = *(const s16x8*)&As[(wr * 64 + i * 16 + l16) * 32 + quad * 8];
      bf[i] = *(const s16x8*)&Bs[(wc * 64 + i * 16 + l16) * 32 + quad * 8];
    }
#pragma unroll
    for (int i = 0; i < 4; ++i)
#pragma unroll
      for (int j = 0; j < 4; ++j)
        acc[i][j] = __builtin_amdgcn_mfma_f32_16x16x32_bf16(af[i], bf[j], acc[i][j], 0, 0, 0);
    __syncthreads();
  }

  if (z != 2) {
#pragma unroll
    for (int j = 0; j < 4; ++j) {
      const int col = n0 + wc * 64 + j * 16 + l16;
      const float bvv = bias[col];
#pragma unroll
      for (int i = 0; i < 4; ++i) {
        const int row0 = m0 + wr * 64 + i * 16 + quad * 4;
#pragma unroll
        for (int r = 0; r < 4; ++r)
          out[(size_t)(row0 + r) * D_ + col] = f2bf((acc[i][j][r] + bvv) * scale);
      }
    }
  } else {
    // stage transposed tile in LDS: Ts[col_local][tok_local]
#pragma unroll
    for (int j = 0; j < 4; ++j) {
      const int cl = wc * 64 + j * 16 + l16;
      const float bvv = bias[n0 + cl];
#pragma unroll
      for (int i = 0; i < 4; ++i) {
        const int tl0 = wr * 64 + i * 16 + quad * 4;
#pragma unroll
        for (int r = 0; r < 4; ++r)
          Ts[cl][tl0 + r] = f2bf(acc[i][j][r] + bvv);
      }
    }
    __syncthreads();
    // coalesced write-out: 16 lanes x 16B = one full 256B Vt row per group
    const int bb = m0 >> 11;            // batch (block fully within one b)
    const int t0 = m0 & (N_ - 1);
#pragma unroll
    for (int it = 0; it < 8; ++it) {
      const int row = it * 16 + (tid >> 4);   // 0..127 (col_local)
      const int seg = tid & 15;               // 16B segment within row
      const int colg = n0 + row;
      const int hh = colg >> 6, dh = colg & 63;
      const s16x8 vv = *(const s16x8*)&Ts[row][seg * 8];
      *(s16x8*)&out[(size_t)((bb * H_ + hh) * DH_ + dh) * N_ + t0 + seg * 8] = vv;
    }
  }
}

// ---- flash attention v10: dual-q + dbuf prefetch + permlane P-redist +
// ones-MFMA li + truncation pack. Measured 48.3-50.8 us, absmax 4.88e-4.
__global__ __launch_bounds__(256, 2)
void attn_kernel(const u16* __restrict__ Q, const u16* __restrict__ K,
                 const u16* __restrict__ Vt, u16* __restrict__ X) {
  __shared__ __align__(16) u16 Ks[2][128 * 64];   // [k][dh] swizzled, dbuf
  __shared__ __align__(16) u16 Vs[2][64 * 128];   // [dh][k] swizzled, dbuf
  const int tid  = threadIdx.x;
  const int wave = tid >> 6, lane = tid & 63;
  const int quad = lane >> 4, l16 = lane & 15;

  const int flat = blockIdx.y * 16 + blockIdx.x;
  const int u = flat & 7, slot = flat >> 3;     // u -> XCD, slot in [0,64)
  const int qb = slot & 15;
  const int bh = u * 4 + (slot >> 4);           // 4 heads per XCD
  const int q0 = qb * 128;
  const int b = bh >> 4, h = bh & 15;

  s16x8 qfa[2], qfb[2];
#pragma unroll
  for (int ks = 0; ks < 2; ++ks) {
    qfa[ks] = *(const s16x8*)&Q[(size_t)(b * N_ + q0 + wave * 16 + l16) * D_ +
                                h * 64 + ks * 32 + quad * 8];
    qfb[ks] = *(const s16x8*)&Q[(size_t)(b * N_ + q0 + 64 + wave * 16 + l16) * D_ +
                                h * 64 + ks * 32 + quad * 8];
  }

  // all-ones A-fragment (bf16 1.0 = 0x3F80)
  s16x8 onesf;
#pragma unroll
  for (int i = 0; i < 8; ++i) onesf[i] = (short)0x3F80;

  f32x4 oa[4], ob[4];
#pragma unroll
  for (int mt = 0; mt < 4; ++mt) { oa[mt] = {0.f, 0.f, 0.f, 0.f}; ob[mt] = {0.f, 0.f, 0.f, 0.f}; }
  f32x4 la = {0.f, 0.f, 0.f, 0.f}, lb = {0.f, 0.f, 0.f, 0.f};

  // 8 gl2lds per thread per stage (4 c4-chunks x {K,V})
  auto stage = [&](int buf, int kt) {
    const int k0 = kt * 128;
#pragma unroll
    for (int c4 = 0; c4 < 4; ++c4) {
      const int p = c4 * 256 + wave * 64 + lane;
      { const int row = p >> 3, cd = p & 7, src = cd ^ (row & 7);
        gl2lds16(&K[(size_t)(b * N_ + k0 + row) * D_ + h * 64 + src * 8],
                 &Ks[buf][(size_t)(c4 * 256 + wave * 64) * 8]); }
      { const int row = p >> 4, cd = p & 15;
        const int src = (cd & 8) | ((cd & 7) ^ (row & 7));
        gl2lds16(&Vt[(size_t)((b * H_ + h) * DH_ + row) * N_ + k0 + src * 8],
                 &Vs[buf][(size_t)(c4 * 256 + wave * 64) * 8]); }
    }
  };

  stage(0, 0);
  int cur = 0;

  for (int kt = 0; kt < N_ / 128; ++kt) {
    if (kt + 1 < N_ / 128) {
      stage(cur ^ 1, kt + 1);                        // prefetch next tile
      asm volatile("s_waitcnt vmcnt(8)" ::: "memory");  // cur's 8 done, next in flight
    } else {
      asm volatile("s_waitcnt vmcnt(0)" ::: "memory");
    }
    __builtin_amdgcn_sched_barrier(0);
    __builtin_amdgcn_s_barrier();

    const u16* ks = &Ks[cur][0];
    const u16* vs = &Vs[cur][0];

    // S^T[k][q]: A = K-frag (m=k), B = Q-frag (n=q); kf shared by both q-sets
    f32x4 sa[8], sb[8];
#pragma unroll
    for (int nt = 0; nt < 8; ++nt) { sa[nt] = {0.f, 0.f, 0.f, 0.f}; sb[nt] = {0.f, 0.f, 0.f, 0.f}; }
    __builtin_amdgcn_s_setprio(1);
#pragma unroll
    for (int nt = 0; nt < 8; ++nt) {
      const int row = nt * 16 + l16;
      const s16x8 kf0 = *(const s16x8*)&ks[row * 64 + ((quad    ) ^ (l16 & 7)) * 8];
      const s16x8 kf1 = *(const s16x8*)&ks[row * 64 + ((4 + quad) ^ (l16 & 7)) * 8];
      sa[nt] = __builtin_amdgcn_mfma_f32_16x16x32_bf16(kf0, qfa[0], sa[nt], 0, 0, 0);
      sa[nt] = __builtin_amdgcn_mfma_f32_16x16x32_bf16(kf1, qfa[1], sa[nt], 0, 0, 0);
      sb[nt] = __builtin_amdgcn_mfma_f32_16x16x32_bf16(kf0, qfb[0], sb[nt], 0, 0, 0);
      sb[nt] = __builtin_amdgcn_mfma_f32_16x16x32_bf16(kf1, qfb[1], sb[nt], 0, 0, 0);
    }
    __builtin_amdgcn_s_setprio(0);

    // p = exp2(s); TRUNCATE to bf16 (verified numerics: downward bias
    // cancels in o/li; li comes from ones-MFMA over the SAME fragments)
    unsigned pka[8][2], pkb[8][2];
#pragma unroll
    for (int nt = 0; nt < 8; ++nt) {
      { const unsigned b0 = __builtin_bit_cast(unsigned, EXP2(sa[nt][0]));
        const unsigned b1 = __builtin_bit_cast(unsigned, EXP2(sa[nt][1]));
        const unsigned b2 = __builtin_bit_cast(unsigned, EXP2(sa[nt][2]));
        const unsigned b3 = __builtin_bit_cast(unsigned, EXP2(sa[nt][3]));
        pka[nt][0] = (b0 >> 16) | (b1 & 0xffff0000u);
        pka[nt][1] = (b2 >> 16) | (b3 & 0xffff0000u); }
      { const unsigned b0 = __builtin_bit_cast(unsigned, EXP2(sb[nt][0]));
        const unsigned b1 = __builtin_bit_cast(unsigned, EXP2(sb[nt][1]));
        const unsigned b2 = __builtin_bit_cast(unsigned, EXP2(sb[nt][2]));
        const unsigned b3 = __builtin_bit_cast(unsigned, EXP2(sb[nt][3]));
        pkb[nt][0] = (b0 >> 16) | (b1 & 0xffff0000u);
        pkb[nt][1] = (b2 >> 16) | (b3 & 0xffff0000u); }
    }

    // O^T += Vt . P^T : vf shared by both q-sets; P redistributed via permlane
#pragma unroll
    for (int k2 = 0; k2 < 4; ++k2) {
      s16x8 vf[4];
#pragma unroll
      for (int mt = 0; mt < 4; ++mt) {
        const int row = mt * 16 + l16;
        const int j8 = k2 * 4 + quad;
        const int cd = (j8 & 8) | ((j8 & 7) ^ (row & 7));
        vf[mt] = *(const s16x8*)&vs[row * 128 + cd * 8];
      }
      unsigned Aa0 = pka[k2 * 2][0], Ba0 = pka[k2 * 2 + 1][0];
      unsigned Aa1 = pka[k2 * 2][1], Ba1 = pka[k2 * 2 + 1][1];
      pl32(Aa0, Ba0); pl16(Aa0, Ba0);
      pl32(Aa1, Ba1); pl16(Aa1, Ba1);
      int4 bda; bda.x = (int)Aa0; bda.y = (int)Aa1; bda.z = (int)Ba0; bda.w = (int)Ba1;
      unsigned Ab0 = pkb[k2 * 2][0], Bb0 = pkb[k2 * 2 + 1][0];
      unsigned Ab1 = pkb[k2 * 2][1], Bb1 = pkb[k2 * 2 + 1][1];
      pl32(Ab0, Bb0); pl16(Ab0, Bb0);
      pl32(Ab1, Bb1); pl16(Ab1, Bb1);
      int4 bdb; bdb.x = (int)Ab0; bdb.y = (int)Ab1; bdb.z = (int)Bb0; bdb.w = (int)Bb1;
      const s16x8 bfa = __builtin_bit_cast(s16x8, bda);
      const s16x8 bfb = __builtin_bit_cast(s16x8, bdb);
      __builtin_amdgcn_s_setprio(1);
#pragma unroll
      for (int mt = 0; mt < 4; ++mt) {
        oa[mt] = __builtin_amdgcn_mfma_f32_16x16x32_bf16(vf[mt], bfa, oa[mt], 0, 0, 0);
        ob[mt] = __builtin_amdgcn_mfma_f32_16x16x32_bf16(vf[mt], bfb, ob[mt], 0, 0, 0);
      }
      la = __builtin_amdgcn_mfma_f32_16x16x32_bf16(onesf, bfa, la, 0, 0, 0);
      lb = __builtin_amdgcn_mfma_f32_16x16x32_bf16(onesf, bfb, lb, 0, 0, 0);
      __builtin_amdgcn_s_setprio(0);
    }

    // all LDS reads of buf[cur] complete before next iter stages into it
    asm volatile("s_waitcnt lgkmcnt(0)" ::: "memory");
    __builtin_amdgcn_s_barrier();
    cur ^= 1;
  }

  // la[0]/lb[0] already hold the full li for this lane's q = l16 column
  const float inva = 1.0f / la[0];
  const float invb = 1.0f / lb[0];
  const int qa = q0 + wave * 16 + l16;
#pragma unroll
  for (int mt = 0; mt < 4; ++mt) {
    ushort4 w;
    w.x = f2bf(oa[mt][0] * inva);
    w.y = f2bf(oa[mt][1] * inva);
    w.z = f2bf(oa[mt][2] * inva);
    w.w = f2bf(oa[mt][3] * inva);
    *(ushort4*)&X[(size_t)(b * N_ + qa) * D_ + h * 64 + mt * 16 + quad * 4] = w;
  }
#pragma unroll
  for (int mt = 0; mt < 4; ++mt) {
    ushort4 w;
    w.x = f2bf(ob[mt][0] * invb);
    w.y = f2bf(ob[mt][1] * invb);
    w.z = f2bf(ob[mt][2] * invb);
    w.w = f2bf(ob[mt][3] * invb);
    *(ushort4*)&X[(size_t)(b * N_ + qa + 64) * D_ + h * 64 + mt * 16 + quad * 4] = w;
  }
}

// ---- out-proj direct from fp32 Wo: XB bf16 via gl2lds, Wo via VGPR pack
// (same f2bf -> bit-identical to cvt path). XCD remap (bijective, 512).
__global__ __launch_bounds__(256, 2)
void out_gemm_f32(const u16* __restrict__ A, const float* __restrict__ W,
                  const float* __restrict__ bias, float* __restrict__ out) {
  __shared__ __align__(16) u16 As[64 * 32];
  __shared__ __align__(16) u16 Bs[128 * 32];
  const int tid  = threadIdx.x;
  const int wave = tid >> 6, lane = tid & 63;
  const int quad = lane >> 4, l16 = lane & 15;
  const int wr = wave >> 1, wc = wave & 1;

  const int flat = blockIdx.y * 8 + blockIdx.x;
  const int u = flat & 7, v = flat >> 3;
  const int bxn = v & 7;
  const int bym = u * 8 + (v >> 3);
  const int m0 = bym * 64, n0 = bxn * 128;

  f32x4 acc[2][4];
#pragma unroll
  for (int i = 0; i < 2; ++i)
#pragma unroll
    for (int j = 0; j < 4; ++j) acc[i][j] = {0.f, 0.f, 0.f, 0.f};

  for (int kt = 0; kt < D_ / 32; ++kt) {
    const int kb = kt * 32;
    { const int c = wave * 64 + lane;
      const int row = c >> 2, col = (c & 3) * 8;
      gl2lds16(&A[(size_t)(m0 + row) * D_ + kb + col], &As[(size_t)(wave * 64) * 8]); }
#pragma unroll
    for (int call = 0; call < 2; ++call) {
      const int c = call * 256 + wave * 64 + lane;
      const int row = c >> 2, col = (c & 3) * 8;
      const float4 w0 = *(const float4*)&W[(size_t)(n0 + row) * D_ + kb + col];
      const float4 w1 = *(const float4*)&W[(size_t)(n0 + row) * D_ + kb + col + 4];
      *(s16x8*)&Bs[c * 8] = pack8(w0, w1);
    }
    __syncthreads();

    s16x8 af[2], bf[4];
#pragma unroll
    for (int i = 0; i < 2; ++i)
      af[i] = *(const s16x8*)&As[(wr * 32 + i * 16 + l16) * 32 + quad * 8];
#pragma unroll
    for (int j = 0; j < 4; ++j)
      bf[j] = *(const s16x8*)&Bs[(wc * 64 + j * 16 + l16) * 32 + quad * 8];
#pragma unroll
    for (int i = 0; i < 2; ++i)
#pragma unroll
      for (int j = 0; j < 4; ++j)
        acc[i][j] = __builtin_amdgcn_mfma_f32_16x16x32_bf16(af[i], bf[j], acc[i][j], 0, 0, 0);
    __syncthreads();
  }

#pragma unroll
  for (int j = 0; j < 4; ++j) {
    const int col = n0 + wc * 64 + j * 16 + l16;
    const float bv = bias[col];
#pragma unroll
    for (int i = 0; i < 2; ++i) {
      const int row0 = m0 + wr * 32 + i * 16 + quad * 4;
#pragma unroll
      for (int r = 0; r < 4; ++r)
        out[(size_t)(row0 + r) * D_ + col] = acc[i][j][r] + bv;
    }
  }
}

extern "C" void kernel_launch(void* const* d_in, const int* in_sizes, int n_in,
                              void* d_out, int out_size, void* d_ws, size_t ws_size,
                              hipStream_t stream) {
  const float* xq = (const float*)d_in[0];
  const float* xk = (const float*)d_in[1];
  const float* xv = (const float*)d_in[2];
  const float* Wq = (const float*)d_in[3];
  const float* bq = (const float*)d_in[4];
  const float* Wk = (const float*)d_in[5];
  const float* bk = (const float*)d_in[6];
  const float* Wv = (const float*)d_in[7];
  const float* bv = (const float*)d_in[8];
  const float* Wo = (const float*)d_in[9];
  const float* bo = (const float*)d_in[10];
  u16*   ws  = (u16*)d_ws;
  float* out = (float*)d_out;

  dim3 blk(256);
  // cvt-free 3-dispatch pipeline (halves staging HBM traffic, one fewer
  // kernel; outputs bit-identical to the cvt+bf16 path).
  hipLaunchKernelGGL(qkv_gemm_f32, dim3(8, 32, 3), blk, 0, stream,
                     xq, xk, xv, Wq, Wk, Wv, bq, bk, bv, ws);
  hipLaunchKernelGGL(attn_kernel, dim3(16, 32), blk, 0, stream,
                     ws + OFF_QB, ws + OFF_KB, ws + OFF_VB, ws + OFF_XB);
  hipLaunchKernelGGL(out_gemm_f32, dim3(8, 64), blk, 0, stream,
                     ws + OFF_XB, Wo, bo, out);
}

// Round 17
// 209.466 us; speedup vs baseline: 1.2706x; 1.2706x over previous
//
#include <hip/hip_runtime.h>

typedef unsigned short u16;
typedef __attribute__((ext_vector_type(8))) short s16x8;
typedef __attribute__((ext_vector_type(4))) float f32x4;
typedef unsigned uint2v __attribute__((ext_vector_type(2)));

#define B_  2
#define N_  2048
#define D_  1024
#define H_  16
#define DH_ 64
#define M_  4096  // B_*N_

#define S_X (M_ * D_)   // 4M
#define S_W (D_ * D_)   // 1M

// Q pre-scale: 1/sqrt(64) folded with log2(e) so softmax uses raw exp2
#define QSCALE 0.1803368801111204f

// ws layout (u16 offsets). Fast path needs 32M u16 = 64 MiB.
#define OFF_QB 0
#define OFF_KB (S_X)
#define OFF_VB (2 * S_X)
#define OFF_XB (3 * S_X)
#define OFF_XQ (4 * S_X)
#define OFF_XK (5 * S_X)
#define OFF_XV (6 * S_X)
#define OFF_WQ (7 * S_X)
#define OFF_WK (7 * S_X + S_W)
#define OFF_WV (7 * S_X + 2 * S_W)
#define OFF_WO (7 * S_X + 3 * S_W)
#define WS_FAST_BYTES ((size_t)(7 * S_X + 4 * S_W) * 2)   // 64 MiB

#if __has_builtin(__builtin_amdgcn_exp2f)
#define EXP2(x) __builtin_amdgcn_exp2f(x)
#else
#define EXP2(x) exp2f(x)
#endif

__device__ __forceinline__ u16 f2bf(float f) {
  unsigned u = __builtin_bit_cast(unsigned, f);
  u += 0x7fffu + ((u >> 16) & 1u);   // RNE
  return (u16)(u >> 16);
}
__device__ __forceinline__ s16x8 pack8(float4 a, float4 b) {
  s16x8 r;
  r[0] = (short)f2bf(a.x); r[1] = (short)f2bf(a.y);
  r[2] = (short)f2bf(a.z); r[3] = (short)f2bf(a.w);
  r[4] = (short)f2bf(b.x); r[5] = (short)f2bf(b.y);
  r[6] = (short)f2bf(b.z); r[7] = (short)f2bf(b.w);
  return r;
}
__device__ __forceinline__ void gl2lds16(const void* g, void* l) {
  __builtin_amdgcn_global_load_lds(
      (const __attribute__((address_space(1))) void*)g,
      (__attribute__((address_space(3))) void*)l, 16, 0, 0);
}
// permlane swaps (VALU pipe): a,b updated in place.
__device__ __forceinline__ void pl32(unsigned &a, unsigned &b) {
#if __has_builtin(__builtin_amdgcn_permlane32_swap)
  uint2v r = __builtin_amdgcn_permlane32_swap(a, b, 0, 0);
  a = r[0]; b = r[1];
#else
  asm("v_permlane32_swap_b32 %0, %1" : "+v"(a), "+v"(b));
#endif
}
__device__ __forceinline__ void pl16(unsigned &a, unsigned &b) {
#if __has_builtin(__builtin_amdgcn_permlane16_swap)
  uint2v r = __builtin_amdgcn_permlane16_swap(a, b, 0, 0);
  a = r[0]; b = r[1];
#else
  asm("v_permlane16_swap_b32 %0, %1" : "+v"(a), "+v"(b));
#endif
}

// ---- fp32 -> bf16 conversion of x_q,x_k,x_v,Wq,Wk,Wv,Wo into ws ----
// (R16 cvt-free path regressed +56us: fp32 operand re-reads blow L2;
// one-touch cvt + bf16 gl2lds staging is strictly better. Kept.)
__global__ __launch_bounds__(256)
void cvt_kernel(const float* __restrict__ p0, const float* __restrict__ p1,
                const float* __restrict__ p2, const float* __restrict__ p3,
                const float* __restrict__ p4, const float* __restrict__ p5,
                const float* __restrict__ p6, u16* __restrict__ ws) {
  const float* src; u16* dst; int n;
  switch (blockIdx.y) {
    case 0:  src = p0; dst = ws + OFF_XQ; n = S_X; break;
    case 1:  src = p1; dst = ws + OFF_XK; n = S_X; break;
    case 2:  src = p2; dst = ws + OFF_XV; n = S_X; break;
    case 3:  src = p3; dst = ws + OFF_WQ; n = S_W; break;
    case 4:  src = p4; dst = ws + OFF_WK; n = S_W; break;
    case 5:  src = p5; dst = ws + OFF_WV; n = S_W; break;
    default: src = p6; dst = ws + OFF_WO; n = S_W; break;
  }
  const int stride = gridDim.x * blockDim.x * 4;
  for (int idx = (blockIdx.x * blockDim.x + threadIdx.x) * 4; idx < n; idx += stride) {
    const float4 v = *(const float4*)&src[idx];
    ushort4 o;
    o.x = f2bf(v.x); o.y = f2bf(v.y); o.z = f2bf(v.z); o.w = f2bf(v.w);
    *(ushort4*)&dst[idx] = o;
  }
}

// ---- fast QKV: all-bf16 m97 structure, both operands via global_load_lds ----
// XCD remap (bijective over 768): all 8 n-tiles sharing one A-panel land on
// ONE XCD so the 256KB A-panel is L2-resident. LDS linear (R14 swizzle
// regressed: staging-bound). z==2 (V): LDS tile-transpose -> coalesced stores.
__global__ __launch_bounds__(256, 3)
void qkv_gemm_bf(const u16* __restrict__ ws_in, const float* __restrict__ bq,
                 const float* __restrict__ bk, const float* __restrict__ bv,
                 u16* __restrict__ ws_out) {
  __shared__ __align__(16) u16 As[128 * 32];
  __shared__ __align__(16) u16 Bs[128 * 32];
  __shared__ __align__(16) u16 Ts[128][136];   // transpose staging (z==2 only)
  const int flat = (blockIdx.z * 32 + blockIdx.y) * 8 + blockIdx.x;
  const int u = flat & 7, v = flat >> 3;        // u -> XCD, v in [0,96)
  const int bxn = v & 7;                        // n-tile
  const int byz = u * 12 + (v >> 3);            // [0,96)
  const int z = byz >> 5, bym = byz & 31;       // z in [0,3), m-tile in [0,32)

  const u16* A = ws_in + OFF_XQ + (size_t)z * S_X;
  const u16* W = ws_in + OFF_WQ + (size_t)z * S_W;
  const float* bias = (z == 0) ? bq : (z == 1) ? bk : bv;
  u16* out = ws_out + (size_t)z * S_X;
  const float scale = (z == 0) ? QSCALE : 1.0f;

  const int tid  = threadIdx.x;
  const int wave = tid >> 6, lane = tid & 63;
  const int quad = lane >> 4, l16 = lane & 15;
  const int wr = wave >> 1, wc = wave & 1;
  const int m0 = bym * 128, n0 = bxn * 128;

  f32x4 acc[4][4];
#pragma unroll
  for (int i = 0; i < 4; ++i)
#pragma unroll
    for (int j = 0; j < 4; ++j) acc[i][j] = {0.f, 0.f, 0.f, 0.f};

  for (int kt = 0; kt < D_ / 32; ++kt) {
    const int kb = kt * 32;
#pragma unroll
    for (int call = 0; call < 2; ++call) {
      const int c = call * 256 + wave * 64 + lane;
      const int row = c >> 2, col8 = (c & 3) * 8;
      gl2lds16(&A[(size_t)(m0 + row) * D_ + kb + col8],
               &As[(size_t)(call * 256 + wave * 64) * 8]);
      gl2lds16(&W[(size_t)(n0 + row) * D_ + kb + col8],
               &Bs[(size_t)(call * 256 + wave * 64) * 8]);
    }
    __syncthreads();

    s16x8 af[4], bf[4];
#pragma unroll
    for (int i = 0; i < 4; ++i) {
      af[i] = *(const s16x8*)&As[(wr * 64 + i * 16 + l16) * 32 + quad * 8];
      bf[i] = *(const s16x8*)&Bs[(wc * 64 + i * 16 + l16) * 32 + quad * 8];
    }
#pragma unroll
    for (int i = 0; i < 4; ++i)
#pragma unroll
      for (int j = 0; j < 4; ++j)
        acc[i][j] = __builtin_amdgcn_mfma_f32_16x16x32_bf16(af[i], bf[j], acc[i][j], 0, 0, 0);
    __syncthreads();
  }

  if (z != 2) {
#pragma unroll
    for (int j = 0; j < 4; ++j) {
      const int col = n0 + wc * 64 + j * 16 + l16;
      const float bvv = bias[col];
#pragma unroll
      for (int i = 0; i < 4; ++i) {
        const int row0 = m0 + wr * 64 + i * 16 + quad * 4;
#pragma unroll
        for (int r = 0; r < 4; ++r)
          out[(size_t)(row0 + r) * D_ + col] = f2bf((acc[i][j][r] + bvv) * scale);
      }
    }
  } else {
    // stage transposed tile in LDS: Ts[col_local][tok_local]
#pragma unroll
    for (int j = 0; j < 4; ++j) {
      const int cl = wc * 64 + j * 16 + l16;
      const float bvv = bias[n0 + cl];
#pragma unroll
      for (int i = 0; i < 4; ++i) {
        const int tl0 = wr * 64 + i * 16 + quad * 4;
#pragma unroll
        for (int r = 0; r < 4; ++r)
          Ts[cl][tl0 + r] = f2bf(acc[i][j][r] + bvv);
      }
    }
    __syncthreads();
    // coalesced write-out: 16 lanes x 16B = one full 256B Vt row per group
    const int bb = m0 >> 11;            // batch (block fully within one b)
    const int t0 = m0 & (N_ - 1);
#pragma unroll
    for (int it = 0; it < 8; ++it) {
      const int row = it * 16 + (tid >> 4);   // 0..127 (col_local)
      const int seg = tid & 15;               // 16B segment within row
      const int colg = n0 + row;
      const int hh = colg >> 6, dh = colg & 63;
      const s16x8 vv = *(const s16x8*)&Ts[row][seg * 8];
      *(s16x8*)&out[(size_t)((bb * H_ + hh) * DH_ + dh) * N_ + t0 + seg * 8] = vv;
    }
  }
}

// ---- fallback QKV: fp32 operands staged via VGPR pack ----
__global__ __launch_bounds__(256, 3)
void qkv_gemm_f32(const float* __restrict__ xq, const float* __restrict__ xk,
                  const float* __restrict__ xv, const float* __restrict__ Wq,
                  const float* __restrict__ Wk, const float* __restrict__ Wv,
                  const float* __restrict__ bq, const float* __restrict__ bk,
                  const float* __restrict__ bv, u16* __restrict__ ws) {
  __shared__ __align__(16) u16 As[128 * 32];
  __shared__ __align__(16) u16 Bs[128 * 32];
  const int flat = (blockIdx.z * 32 + blockIdx.y) * 8 + blockIdx.x;
  const int u = flat & 7, v = flat >> 3;
  const int bxn = v & 7;
  const int byz = u * 12 + (v >> 3);
  const int z = byz >> 5, bym = byz & 31;

  const float* A    = (z == 0) ? xq : (z == 1) ? xk : xv;
  const float* W    = (z == 0) ? Wq : (z == 1) ? Wk : Wv;
  const float* bias = (z == 0) ? bq : (z == 1) ? bk : bv;
  u16* out = ws + (size_t)z * S_X;
  const float scale = (z == 0) ? QSCALE : 1.0f;

  const int tid  = threadIdx.x;
  const int wave = tid >> 6, lane = tid & 63;
  const int quad = lane >> 4, l16 = lane & 15;
  const int wr = wave >> 1, wc = wave & 1;
  const int m0 = bym * 128, n0 = bxn * 128;

  f32x4 acc[4][4];
#pragma unroll
  for (int i = 0; i < 4; ++i)
#pragma unroll
    for (int j = 0; j < 4; ++j) acc[i][j] = {0.f, 0.f, 0.f, 0.f};

  for (int kt = 0; kt < D_ / 32; ++kt) {
    const int kb = kt * 32;
#pragma unroll
    for (int call = 0; call < 2; ++call) {
      const int c = call * 256 + wave * 64 + lane;
      const int row = c >> 2, col = (c & 3) * 8;
      const float4 a0 = *(const float4*)&A[(size_t)(m0 + row) * D_ + kb + col];
      const float4 a1 = *(const float4*)&A[(size_t)(m0 + row) * D_ + kb + col + 4];
      const float4 w0 = *(const float4*)&W[(size_t)(n0 + row) * D_ + kb + col];
      const float4 w1 = *(const float4*)&W[(size_t)(n0 + row) * D_ + kb + col + 4];
      *(s16x8*)&As[c * 8] = pack8(a0, a1);
      *(s16x8*)&Bs[c * 8] = pack8(w0, w1);
    }
    __syncthreads();

    s16x8 af[4], bf[4];
#pragma unroll
    for (int i = 0; i < 4; ++i) {
      af[i] = *(const s16x8*)&As[(wr * 64 + i * 16 + l16) * 32 + quad * 8];
      bf[i] = *(const s16x8*)&Bs[(wc * 64 + i * 16 + l16) * 32 + quad * 8];
    }
#pragma unroll
    for (int i = 0; i < 4; ++i)
#pragma unroll
      for (int j = 0; j < 4; ++j)
        acc[i][j] = __builtin_amdgcn_mfma_f32_16x16x32_bf16(af[i], bf[j], acc[i][j], 0, 0, 0);
    __syncthreads();
  }

  if (z != 2) {
#pragma unroll
    for (int j = 0; j < 4; ++j) {
      const int col = n0 + wc * 64 + j * 16 + l16;
      const float bvv = bias[col];
#pragma unroll
      for (int i = 0; i < 4; ++i) {
        const int row0 = m0 + wr * 64 + i * 16 + quad * 4;
#pragma unroll
        for (int r = 0; r < 4; ++r)
          out[(size_t)(row0 + r) * D_ + col] = f2bf((acc[i][j][r] + bvv) * scale);
      }
    }
  } else {
#pragma unroll
    for (int j = 0; j < 4; ++j) {
      const int col = n0 + wc * 64 + j * 16 + l16;
      const int h = col >> 6, dh = col & 63;
      const float bvv = bias[col];
#pragma unroll
      for (int i = 0; i < 4; ++i) {
        const int row0 = m0 + wr * 64 + i * 16 + quad * 4;
#pragma unroll
        for (int r = 0; r < 4; ++r) {
          const int tok = row0 + r;
          const int b = tok >> 11, t = tok & (N_ - 1);
          out[(size_t)((b * H_ + h) * DH_ + dh) * N_ + t] = f2bf(acc[i][j][r] + bvv);
        }
      }
    }
  }
}

// ---- flash attention v10: dual-q + dbuf prefetch + permlane P-redist +
// ones-MFMA li + truncation pack. Measured 48.3-50.8 us, absmax 4.88e-4.
__global__ __launch_bounds__(256, 2)
void attn_kernel(const u16* __restrict__ Q, const u16* __restrict__ K,
                 const u16* __restrict__ Vt, u16* __restrict__ X) {
  __shared__ __align__(16) u16 Ks[2][128 * 64];   // [k][dh] swizzled, dbuf
  __shared__ __align__(16) u16 Vs[2][64 * 128];   // [dh][k] swizzled, dbuf
  const int tid  = threadIdx.x;
  const int wave = tid >> 6, lane = tid & 63;
  const int quad = lane >> 4, l16 = lane & 15;

  const int flat = blockIdx.y * 16 + blockIdx.x;
  const int u = flat & 7, slot = flat >> 3;     // u -> XCD, slot in [0,64)
  const int qb = slot & 15;
  const int bh = u * 4 + (slot >> 4);           // 4 heads per XCD
  const int q0 = qb * 128;
  const int b = bh >> 4, h = bh & 15;

  s16x8 qfa[2], qfb[2];
#pragma unroll
  for (int ks = 0; ks < 2; ++ks) {
    qfa[ks] = *(const s16x8*)&Q[(size_t)(b * N_ + q0 + wave * 16 + l16) * D_ +
                                h * 64 + ks * 32 + quad * 8];
    qfb[ks] = *(const s16x8*)&Q[(size_t)(b * N_ + q0 + 64 + wave * 16 + l16) * D_ +
                                h * 64 + ks * 32 + quad * 8];
  }

  // all-ones A-fragment (bf16 1.0 = 0x3F80)
  s16x8 onesf;
#pragma unroll
  for (int i = 0; i < 8; ++i) onesf[i] = (short)0x3F80;

  f32x4 oa[4], ob[4];
#pragma unroll
  for (int mt = 0; mt < 4; ++mt) { oa[mt] = {0.f, 0.f, 0.f, 0.f}; ob[mt] = {0.f, 0.f, 0.f, 0.f}; }
  f32x4 la = {0.f, 0.f, 0.f, 0.f}, lb = {0.f, 0.f, 0.f, 0.f};

  // 8 gl2lds per thread per stage (4 c4-chunks x {K,V})
  auto stage = [&](int buf, int kt) {
    const int k0 = kt * 128;
#pragma unroll
    for (int c4 = 0; c4 < 4; ++c4) {
      const int p = c4 * 256 + wave * 64 + lane;
      { const int row = p >> 3, cd = p & 7, src = cd ^ (row & 7);
        gl2lds16(&K[(size_t)(b * N_ + k0 + row) * D_ + h * 64 + src * 8],
                 &Ks[buf][(size_t)(c4 * 256 + wave * 64) * 8]); }
      { const int row = p >> 4, cd = p & 15;
        const int src = (cd & 8) | ((cd & 7) ^ (row & 7));
        gl2lds16(&Vt[(size_t)((b * H_ + h) * DH_ + row) * N_ + k0 + src * 8],
                 &Vs[buf][(size_t)(c4 * 256 + wave * 64) * 8]); }
    }
  };

  stage(0, 0);
  int cur = 0;

  for (int kt = 0; kt < N_ / 128; ++kt) {
    if (kt + 1 < N_ / 128) {
      stage(cur ^ 1, kt + 1);                        // prefetch next tile
      asm volatile("s_waitcnt vmcnt(8)" ::: "memory");  // cur's 8 done, next in flight
    } else {
      asm volatile("s_waitcnt vmcnt(0)" ::: "memory");
    }
    __builtin_amdgcn_sched_barrier(0);
    __builtin_amdgcn_s_barrier();

    const u16* ks = &Ks[cur][0];
    const u16* vs = &Vs[cur][0];

    // S^T[k][q]: A = K-frag (m=k), B = Q-frag (n=q); kf shared by both q-sets
    f32x4 sa[8], sb[8];
#pragma unroll
    for (int nt = 0; nt < 8; ++nt) { sa[nt] = {0.f, 0.f, 0.f, 0.f}; sb[nt] = {0.f, 0.f, 0.f, 0.f}; }
    __builtin_amdgcn_s_setprio(1);
#pragma unroll
    for (int nt = 0; nt < 8; ++nt) {
      const int row = nt * 16 + l16;
      const s16x8 kf0 = *(const s16x8*)&ks[row * 64 + ((quad    ) ^ (l16 & 7)) * 8];
      const s16x8 kf1 = *(const s16x8*)&ks[row * 64 + ((4 + quad) ^ (l16 & 7)) * 8];
      sa[nt] = __builtin_amdgcn_mfma_f32_16x16x32_bf16(kf0, qfa[0], sa[nt], 0, 0, 0);
      sa[nt] = __builtin_amdgcn_mfma_f32_16x16x32_bf16(kf1, qfa[1], sa[nt], 0, 0, 0);
      sb[nt] = __builtin_amdgcn_mfma_f32_16x16x32_bf16(kf0, qfb[0], sb[nt], 0, 0, 0);
      sb[nt] = __builtin_amdgcn_mfma_f32_16x16x32_bf16(kf1, qfb[1], sb[nt], 0, 0, 0);
    }
    __builtin_amdgcn_s_setprio(0);

    // p = exp2(s); TRUNCATE to bf16 (verified numerics: downward bias
    // cancels in o/li; li comes from ones-MFMA over the SAME fragments)
    unsigned pka[8][2], pkb[8][2];
#pragma unroll
    for (int nt = 0; nt < 8; ++nt) {
      { const unsigned b0 = __builtin_bit_cast(unsigned, EXP2(sa[nt][0]));
        const unsigned b1 = __builtin_bit_cast(unsigned, EXP2(sa[nt][1]));
        const unsigned b2 = __builtin_bit_cast(unsigned, EXP2(sa[nt][2]));
        const unsigned b3 = __builtin_bit_cast(unsigned, EXP2(sa[nt][3]));
        pka[nt][0] = (b0 >> 16) | (b1 & 0xffff0000u);
        pka[nt][1] = (b2 >> 16) | (b3 & 0xffff0000u); }
      { const unsigned b0 = __builtin_bit_cast(unsigned, EXP2(sb[nt][0]));
        const unsigned b1 = __builtin_bit_cast(unsigned, EXP2(sb[nt][1]));
        const unsigned b2 = __builtin_bit_cast(unsigned, EXP2(sb[nt][2]));
        const unsigned b3 = __builtin_bit_cast(unsigned, EXP2(sb[nt][3]));
        pkb[nt][0] = (b0 >> 16) | (b1 & 0xffff0000u);
        pkb[nt][1] = (b2 >> 16) | (b3 & 0xffff0000u); }
    }

    // O^T += Vt . P^T : vf shared by both q-sets; P redistributed via permlane
#pragma unroll
    for (int k2 = 0; k2 < 4; ++k2) {
      s16x8 vf[4];
#pragma unroll
      for (int mt = 0; mt < 4; ++mt) {
        const int row = mt * 16 + l16;
        const int j8 = k2 * 4 + quad;
        const int cd = (j8 & 8) | ((j8 & 7) ^ (row & 7));
        vf[mt] = *(const s16x8*)&vs[row * 128 + cd * 8];
      }
      unsigned Aa0 = pka[k2 * 2][0], Ba0 = pka[k2 * 2 + 1][0];
      unsigned Aa1 = pka[k2 * 2][1], Ba1 = pka[k2 * 2 + 1][1];
      pl32(Aa0, Ba0); pl16(Aa0, Ba0);
      pl32(Aa1, Ba1); pl16(Aa1, Ba1);
      int4 bda; bda.x = (int)Aa0; bda.y = (int)Aa1; bda.z = (int)Ba0; bda.w = (int)Ba1;
      unsigned Ab0 = pkb[k2 * 2][0], Bb0 = pkb[k2 * 2 + 1][0];
      unsigned Ab1 = pkb[k2 * 2][1], Bb1 = pkb[k2 * 2 + 1][1];
      pl32(Ab0, Bb0); pl16(Ab0, Bb0);
      pl32(Ab1, Bb1); pl16(Ab1, Bb1);
      int4 bdb; bdb.x = (int)Ab0; bdb.y = (int)Ab1; bdb.z = (int)Bb0; bdb.w = (int)Bb1;
      const s16x8 bfa = __builtin_bit_cast(s16x8, bda);
      const s16x8 bfb = __builtin_bit_cast(s16x8, bdb);
      __builtin_amdgcn_s_setprio(1);
#pragma unroll
      for (int mt = 0; mt < 4; ++mt) {
        oa[mt] = __builtin_amdgcn_mfma_f32_16x16x32_bf16(vf[mt], bfa, oa[mt], 0, 0, 0);
        ob[mt] = __builtin_amdgcn_mfma_f32_16x16x32_bf16(vf[mt], bfb, ob[mt], 0, 0, 0);
      }
      la = __builtin_amdgcn_mfma_f32_16x16x32_bf16(onesf, bfa, la, 0, 0, 0);
      lb = __builtin_amdgcn_mfma_f32_16x16x32_bf16(onesf, bfb, lb, 0, 0, 0);
      __builtin_amdgcn_s_setprio(0);
    }

    // all LDS reads of buf[cur] complete before next iter stages into it
    asm volatile("s_waitcnt lgkmcnt(0)" ::: "memory");
    __builtin_amdgcn_s_barrier();
    cur ^= 1;
  }

  // la[0]/lb[0] already hold the full li for this lane's q = l16 column
  const float inva = 1.0f / la[0];
  const float invb = 1.0f / lb[0];
  const int qa = q0 + wave * 16 + l16;
#pragma unroll
  for (int mt = 0; mt < 4; ++mt) {
    ushort4 w;
    w.x = f2bf(oa[mt][0] * inva);
    w.y = f2bf(oa[mt][1] * inva);
    w.z = f2bf(oa[mt][2] * inva);
    w.w = f2bf(oa[mt][3] * inva);
    *(ushort4*)&X[(size_t)(b * N_ + qa) * D_ + h * 64 + mt * 16 + quad * 4] = w;
  }
#pragma unroll
  for (int mt = 0; mt < 4; ++mt) {
    ushort4 w;
    w.x = f2bf(ob[mt][0] * invb);
    w.y = f2bf(ob[mt][1] * invb);
    w.z = f2bf(ob[mt][2] * invb);
    w.w = f2bf(ob[mt][3] * invb);
    *(ushort4*)&X[(size_t)(b * N_ + qa + 64) * D_ + h * 64 + mt * 16 + quad * 4] = w;
  }
}

// ---- fast out-proj: XB and Wo both bf16 via gl2lds; 64x128 tile; fp32 out ----
// XCD remap: the 8 n-tiles sharing an A-panel pin to one XCD (bijective, 512).
__global__ __launch_bounds__(256, 2)
void out_gemm_bf(const u16* __restrict__ A, const u16* __restrict__ W,
                 const float* __restrict__ bias, float* __restrict__ out) {
  __shared__ __align__(16) u16 As[64 * 32];
  __shared__ __align__(16) u16 Bs[128 * 32];
  const int tid  = threadIdx.x;
  const int wave = tid >> 6, lane = tid & 63;
  const int quad = lane >> 4, l16 = lane & 15;
  const int wr = wave >> 1, wc = wave & 1;

  const int flat = blockIdx.y * 8 + blockIdx.x;
  const int u = flat & 7, v = flat >> 3;        // v in [0,64)
  const int bxn = v & 7;
  const int bym = u * 8 + (v >> 3);             // [0,64)
  const int m0 = bym * 64, n0 = bxn * 128;

  f32x4 acc[2][4];
#pragma unroll
  for (int i = 0; i < 2; ++i)
#pragma unroll
    for (int j = 0; j < 4; ++j) acc[i][j] = {0.f, 0.f, 0.f, 0.f};

  for (int kt = 0; kt < D_ / 32; ++kt) {
    const int kb = kt * 32;
    { const int c = wave * 64 + lane;
      const int row = c >> 2, col8 = (c & 3) * 8;
      gl2lds16(&A[(size_t)(m0 + row) * D_ + kb + col8], &As[(size_t)(wave * 64) * 8]); }
#pragma unroll
    for (int call = 0; call < 2; ++call) {
      const int c = call * 256 + wave * 64 + lane;
      const int row = c >> 2, col8 = (c & 3) * 8;
      gl2lds16(&W[(size_t)(n0 + row) * D_ + kb + col8],
               &Bs[(size_t)(call * 256 + wave * 64) * 8]);
    }
    __syncthreads();

    s16x8 af[2], bf[4];
#pragma unroll
    for (int i = 0; i < 2; ++i)
      af[i] = *(const s16x8*)&As[(wr * 32 + i * 16 + l16) * 32 + quad * 8];
#pragma unroll
    for (int j = 0; j < 4; ++j)
      bf[j] = *(const s16x8*)&Bs[(wc * 64 + j * 16 + l16) * 32 + quad * 8];
#pragma unroll
    for (int i = 0; i < 2; ++i)
#pragma unroll
      for (int j = 0; j < 4; ++j)
        acc[i][j] = __builtin_amdgcn_mfma_f32_16x16x32_bf16(af[i], bf[j], acc[i][j], 0, 0, 0);
    __syncthreads();
  }

#pragma unroll
  for (int j = 0; j < 4; ++j) {
    const int col = n0 + wc * 64 + j * 16 + l16;
    const float bv = bias[col];
#pragma unroll
    for (int i = 0; i < 2; ++i) {
      const int row0 = m0 + wr * 32 + i * 16 + quad * 4;
#pragma unroll
      for (int r = 0; r < 4; ++r)
        out[(size_t)(row0 + r) * D_ + col] = acc[i][j][r] + bv;
    }
  }
}

// ---- fallback out-proj: W fp32 staged via pack ----
__global__ __launch_bounds__(256, 2)
void out_gemm_f32(const u16* __restrict__ A, const float* __restrict__ W,
                  const float* __restrict__ bias, float* __restrict__ out) {
  __shared__ __align__(16) u16 As[64 * 32];
  __shared__ __align__(16) u16 Bs[128 * 32];
  const int tid  = threadIdx.x;
  const int wave = tid >> 6, lane = tid & 63;
  const int quad = lane >> 4, l16 = lane & 15;
  const int wr = wave >> 1, wc = wave & 1;

  const int flat = blockIdx.y * 8 + blockIdx.x;
  const int u = flat & 7, v = flat >> 3;
  const int bxn = v & 7;
  const int bym = u * 8 + (v >> 3);
  const int m0 = bym * 64, n0 = bxn * 128;

  f32x4 acc[2][4];
#pragma unroll
  for (int i = 0; i < 2; ++i)
#pragma unroll
    for (int j = 0; j < 4; ++j) acc[i][j] = {0.f, 0.f, 0.f, 0.f};

  for (int kt = 0; kt < D_ / 32; ++kt) {
    const int kb = kt * 32;
    { const int c = wave * 64 + lane;
      const int row = c >> 2, col = (c & 3) * 8;
      gl2lds16(&A[(size_t)(m0 + row) * D_ + kb + col], &As[(size_t)(wave * 64) * 8]); }
#pragma unroll
    for (int call = 0; call < 2; ++call) {
      const int c = call * 256 + wave * 64 + lane;
      const int row = c >> 2, col = (c & 3) * 8;
      const float4 w0 = *(const float4*)&W[(size_t)(n0 + row) * D_ + kb + col];
      const float4 w1 = *(const float4*)&W[(size_t)(n0 + row) * D_ + kb + col + 4];
      *(s16x8*)&Bs[c * 8] = pack8(w0, w1);
    }
    __syncthreads();

    s16x8 af[2], bf[4];
#pragma unroll
    for (int i = 0; i < 2; ++i)
      af[i] = *(const s16x8*)&As[(wr * 32 + i * 16 + l16) * 32 + quad * 8];
#pragma unroll
    for (int j = 0; j < 4; ++j)
      bf[j] = *(const s16x8*)&Bs[(wc * 64 + j * 16 + l16) * 32 + quad * 8];
#pragma unroll
    for (int i = 0; i < 2; ++i)
#pragma unroll
      for (int j = 0; j < 4; ++j)
        acc[i][j] = __builtin_amdgcn_mfma_f32_16x16x32_bf16(af[i], bf[j], acc[i][j], 0, 0, 0);
    __syncthreads();
  }

#pragma unroll
  for (int j = 0; j < 4; ++j) {
    const int col = n0 + wc * 64 + j * 16 + l16;
    const float bv = bias[col];
#pragma unroll
    for (int i = 0; i < 2; ++i) {
      const int row0 = m0 + wr * 32 + i * 16 + quad * 4;
#pragma unroll
      for (int r = 0; r < 4; ++r)
        out[(size_t)(row0 + r) * D_ + col] = acc[i][j][r] + bv;
    }
  }
}

extern "C" void kernel_launch(void* const* d_in, const int* in_sizes, int n_in,
                              void* d_out, int out_size, void* d_ws, size_t ws_size,
                              hipStream_t stream) {
  const float* xq = (const float*)d_in[0];
  const float* xk = (const float*)d_in[1];
  const float* xv = (const float*)d_in[2];
  const float* Wq = (const float*)d_in[3];
  const float* bq = (const float*)d_in[4];
  const float* Wk = (const float*)d_in[5];
  const float* bk = (const float*)d_in[6];
  const float* Wv = (const float*)d_in[7];
  const float* bv = (const float*)d_in[8];
  const float* Wo = (const float*)d_in[9];
  const float* bo = (const float*)d_in[10];
  u16*   ws  = (u16*)d_ws;
  float* out = (float*)d_out;

  dim3 blk(256);
  if (ws_size >= WS_FAST_BYTES) {
    hipLaunchKernelGGL(cvt_kernel, dim3(256, 7), blk, 0, stream,
                       xq, xk, xv, Wq, Wk, Wv, Wo, ws);
    hipLaunchKernelGGL(qkv_gemm_bf, dim3(8, 32, 3), blk, 0, stream,
                       ws, bq, bk, bv, ws + OFF_QB);
    hipLaunchKernelGGL(attn_kernel, dim3(16, 32), blk, 0, stream,
                       ws + OFF_QB, ws + OFF_KB, ws + OFF_VB, ws + OFF_XB);
    hipLaunchKernelGGL(out_gemm_bf, dim3(8, 64), blk, 0, stream,
                       ws + OFF_XB, ws + OFF_WO, bo, out);
  } else {
    hipLaunchKernelGGL(qkv_gemm_f32, dim3(8, 32, 3), blk, 0, stream,
                       xq, xk, xv, Wq, Wk, Wv, bq, bk, bv, ws);
    hipLaunchKernelGGL(attn_kernel, dim3(16, 32), blk, 0, stream,
                       ws + OFF_QB, ws + OFF_KB, ws + OFF_VB, ws + OFF_XB);
    hipLaunchKernelGGL(out_gemm_f32, dim3(8, 64), blk, 0, stream,
                       ws + OFF_XB, Wo, bo, out);
  }
}